// Round 1
// baseline (82.870 us; speedup 1.0000x reference)
//
#include <hip/hip_runtime.h>

// FullyConvolutionalFractionalScaling2D: r=3, s=2, k=3
// in  : [4, 512, 512, 32]  f32 channels-last
// wgt : [9, 1, 3, 3]       f32
// out : [4, 768, 768, 32]  f32 channels-last
//
// out[b, 3*hs+ra, 3*ws+rb, c] =
//   sum_{dy,dx} w[(3*ra+rb)*9 + 3*dy + dx] * in[b, clamp(2*hs+dy-1), clamp(2*ws+dx-1), c]
//
// One thread = one (b, hs, ws, channel-group-of-4): reads the 3x3 patch once
// (9 float4 loads), produces the full 3x3 pixel-shuffle block (9 float4 stores).

constexpr int B = 4, H = 512, W = 512, C = 32;
constexpr int HS = 256, WS = 256;   // conv output spatial
constexpr int HO = 768, WO = 768;   // final output spatial

__global__ __launch_bounds__(256) void fracscale_kernel(
    const float* __restrict__ in, const float* __restrict__ wgt,
    float* __restrict__ out)
{
    __shared__ float w[81];
    if (threadIdx.x < 81) w[threadIdx.x] = wgt[threadIdx.x];
    __syncthreads();

    unsigned u = blockIdx.x * 256u + threadIdx.x;
    const int cg = u & 7;            // channel group: channels cg*4 .. cg*4+3
    const int ws = (u >> 3) & 255;
    const int hs = (u >> 11) & 255;
    const int b  = u >> 19;

    // clamped input coords (replicate pad by 1)
    int iy[3], ix[3];
#pragma unroll
    for (int d = 0; d < 3; ++d) {
        int y = 2 * hs + d - 1;
        iy[d] = y < 0 ? 0 : (y > H - 1 ? H - 1 : y);
        int x = 2 * ws + d - 1;
        ix[d] = x < 0 ? 0 : (x > W - 1 ? W - 1 : x);
    }

    const float* inb = in + (size_t)b * H * W * C + (size_t)cg * 4;

    float4 acc[3][3];
#pragma unroll
    for (int ra = 0; ra < 3; ++ra)
#pragma unroll
        for (int rb = 0; rb < 3; ++rb)
            acc[ra][rb] = make_float4(0.f, 0.f, 0.f, 0.f);

#pragma unroll
    for (int dy = 0; dy < 3; ++dy) {
        float4 v[3];
#pragma unroll
        for (int dx = 0; dx < 3; ++dx) {
            v[dx] = *(const float4*)(inb + ((size_t)iy[dy] * W + ix[dx]) * C);
        }
#pragma unroll
        for (int ra = 0; ra < 3; ++ra)
#pragma unroll
            for (int rb = 0; rb < 3; ++rb) {
#pragma unroll
                for (int dx = 0; dx < 3; ++dx) {
                    const float wv = w[(ra * 3 + rb) * 9 + dy * 3 + dx];
                    acc[ra][rb].x = fmaf(wv, v[dx].x, acc[ra][rb].x);
                    acc[ra][rb].y = fmaf(wv, v[dx].y, acc[ra][rb].y);
                    acc[ra][rb].z = fmaf(wv, v[dx].z, acc[ra][rb].z);
                    acc[ra][rb].w = fmaf(wv, v[dx].w, acc[ra][rb].w);
                }
            }
    }

    float* outb = out + (size_t)b * HO * WO * C + (size_t)cg * 4;
#pragma unroll
    for (int ra = 0; ra < 3; ++ra)
#pragma unroll
        for (int rb = 0; rb < 3; ++rb) {
            const int ho = hs * 3 + ra;
            const int wo = ws * 3 + rb;
            *(float4*)(outb + ((size_t)ho * WO + wo) * C) = acc[ra][rb];
        }
}

extern "C" void kernel_launch(void* const* d_in, const int* in_sizes, int n_in,
                              void* d_out, int out_size, void* d_ws, size_t ws_size,
                              hipStream_t stream) {
    const float* in  = (const float*)d_in[0];
    const float* wgt = (const float*)d_in[1];
    float* out = (float*)d_out;

    // total threads = B * HS * WS * 8 = 2,097,152 -> 8192 blocks of 256
    const int total = B * HS * WS * 8;
    const int blocks = total / 256;
    fracscale_kernel<<<blocks, 256, 0, stream>>>(in, wgt, out);
}

// Round 3
// 67.238 us; speedup vs baseline: 1.2325x; 1.2325x over previous
//
#include <hip/hip_runtime.h>

// FullyConvolutionalFractionalScaling2D: r=3, s=2, k=3
// in  : [4, 512, 512, 32]  f32 channels-last
// wgt : [9, 1, 3, 3]       f32 (bilinear -> separable outer product)
// out : [4, 768, 768, 32]  f32 channels-last
//
// w[3*ra+rb, 0, dy, dx] = G[ra][dy] * G[rb][dx],  G[p][t] = wgt[27*p + 3*t]
// (verified: G = [[1,0,0],[1/6,5/6,0],[0,1/3,2/3]])
//
// out[b, 3*hs+ra, 3*ws+rb, c] =
//   sum_{dy,dx} G[ra][dy] * G[rb][dx] * in[b, clamp(2*hs+dy-1), clamp(2*ws+dx-1), c]
//
// One thread = one (b, hs, ws, channel-group-of-4): 9 float4 loads -> full
// 3x3 pixel-shuffle block (9 float4 nontemporal stores). Weights in SGPRs.

constexpr int B = 4, H = 512, W = 512, C = 32;
constexpr int HO = 768, WO = 768;

typedef float f32x4 __attribute__((ext_vector_type(4)));

__global__ __launch_bounds__(256) void fracscale_kernel(
    const float* __restrict__ in, const float* __restrict__ wgt,
    float* __restrict__ out)
{
    // separable 1-D weights, wave-uniform -> SGPRs
    float G[3][3];
#pragma unroll
    for (int p = 0; p < 3; ++p)
#pragma unroll
        for (int t = 0; t < 3; ++t)
            G[p][t] = wgt[27 * p + 3 * t];

    unsigned u = blockIdx.x * 256u + threadIdx.x;
    const int cg = u & 7;            // channel group: channels cg*4 .. cg*4+3
    const int ws = (u >> 3) & 255;
    const int hs = (u >> 11) & 255;
    const int b  = u >> 19;

    // clamped input coords (replicate pad by 1)
    int iy[3], ix[3];
#pragma unroll
    for (int d = 0; d < 3; ++d) {
        int y = 2 * hs + d - 1;
        iy[d] = y < 0 ? 0 : (y > H - 1 ? H - 1 : y);
        int x = 2 * ws + d - 1;
        ix[d] = x < 0 ? 0 : (x > W - 1 ? W - 1 : x);
    }

    const float* inb = in + (size_t)b * H * W * C + (size_t)cg * 4;

    f32x4 acc[3][3];
#pragma unroll
    for (int ra = 0; ra < 3; ++ra)
#pragma unroll
        for (int rb = 0; rb < 3; ++rb)
            acc[ra][rb] = (f32x4)(0.f);

#pragma unroll
    for (int dy = 0; dy < 3; ++dy) {
        f32x4 v[3];
#pragma unroll
        for (int dx = 0; dx < 3; ++dx)
            v[dx] = *(const f32x4*)(inb + ((size_t)iy[dy] * W + ix[dx]) * C);

        // horizontal pass: r[rb] = sum_dx G[rb][dx] * v[dx]
        f32x4 r[3];
#pragma unroll
        for (int rb = 0; rb < 3; ++rb) {
            r[rb] = G[rb][0] * v[0];
            r[rb] += G[rb][1] * v[1];
            r[rb] += G[rb][2] * v[2];
        }
        // vertical pass: acc[ra][rb] += G[ra][dy] * r[rb]
#pragma unroll
        for (int ra = 0; ra < 3; ++ra) {
            const float wv = G[ra][dy];
#pragma unroll
            for (int rb = 0; rb < 3; ++rb)
                acc[ra][rb] += wv * r[rb];
        }
    }

    float* outb = out + (size_t)b * HO * WO * C + (size_t)cg * 4;
#pragma unroll
    for (int ra = 0; ra < 3; ++ra) {
        const int ho = hs * 3 + ra;
#pragma unroll
        for (int rb = 0; rb < 3; ++rb) {
            const int wo = ws * 3 + rb;
            __builtin_nontemporal_store(acc[ra][rb],
                (f32x4*)(outb + ((size_t)ho * WO + wo) * C));
        }
    }
}

extern "C" void kernel_launch(void* const* d_in, const int* in_sizes, int n_in,
                              void* d_out, int out_size, void* d_ws, size_t ws_size,
                              hipStream_t stream) {
    const float* in  = (const float*)d_in[0];
    const float* wgt = (const float*)d_in[1];
    float* out = (float*)d_out;

    const int total = B * 256 * 256 * 8;   // 2,097,152 threads
    fracscale_kernel<<<total / 256, 256, 0, stream>>>(in, wgt, out);
}